// Round 17
// baseline (639.663 us; speedup 1.0000x reference)
//
#include <hip/hip_runtime.h>
#include <math.h>

// Shapes: B=2, T=2048, D=1024, H=8, S=32, Dh=128, 3D=3072, B*T=4096
// Round-16 structure minus attn_combine: attnw_gemmo's gemm_out segment
// normalizes accf inline (bit-identical to the old combine+aout16 path),
// and its attn_write segment reads lpart directly.  5 launches.

typedef __attribute__((ext_vector_type(8))) short s16x8;
typedef __attribute__((ext_vector_type(4))) short s16x4;
typedef __attribute__((ext_vector_type(4))) float f32x4;

__device__ inline short f2bf(float f) {
  union { float f; unsigned u; } v; v.f = f;
  unsigned r = v.u + 0x7FFFu + ((v.u >> 16) & 1u);
  return (short)(r >> 16);
}
#define MFMA_BF16(a, b, c) __builtin_amdgcn_mfma_f32_16x16x32_bf16((a), (b), (c), 0, 0, 0)

// ---------------------------------------------------------------------------
// Fused prep (round-8 exact).
// ---------------------------------------------------------------------------
__device__ inline void transpose_tile32(const float* __restrict__ W,
                                        short* __restrict__ Wt, int K, int N,
                                        int n0, int k0) {
  __shared__ float tile[32][33];
  const int r = threadIdx.x >> 3, c4 = (threadIdx.x & 7) * 4;
  float4 v = *(const float4*)(W + (size_t)(k0 + r) * N + n0 + c4);
  tile[r][c4 + 0] = v.x; tile[r][c4 + 1] = v.y;
  tile[r][c4 + 2] = v.z; tile[r][c4 + 3] = v.w;
  __syncthreads();
  s16x4 o;
  o[0] = f2bf(tile[c4 + 0][r]);
  o[1] = f2bf(tile[c4 + 1][r]);
  o[2] = f2bf(tile[c4 + 2][r]);
  o[3] = f2bf(tile[c4 + 3][r]);
  *(s16x4*)(Wt + (size_t)(n0 + r) * K + k0 + c4) = o;
}

__global__ __launch_bounds__(256) void prep_fused(
    const float* __restrict__ x, short* __restrict__ x16,
    const float* __restrict__ Wqkv, short* __restrict__ Wqt16,
    const float* __restrict__ Wout, short* __restrict__ Wot16,
    const float* __restrict__ ctr, const float* __restrict__ ls,
    const float* __restrict__ la, short* __restrict__ c16,
    float* __restrict__ csq, float* __restrict__ inv2, float* __restrict__ amp) {
  const int bx = blockIdx.x;
  if (bx < 4096) {
    int i = bx * 256 + threadIdx.x;
    float4 v = ((const float4*)x)[i];
    s16x4 o;
    o[0] = f2bf(v.x); o[1] = f2bf(v.y); o[2] = f2bf(v.z); o[3] = f2bf(v.w);
    ((s16x4*)x16)[i] = o;
  } else if (bx < 7168) {
    int idx = bx - 4096;
    transpose_tile32(Wqkv, Wqt16, 1024, 3072, (idx % 96) * 32, (idx / 96) * 32);
  } else if (bx < 8192) {
    int idx = bx - 7168;
    transpose_tile32(Wout, Wot16, 1024, 1024, (idx % 32) * 32, (idx / 32) * 32);
  } else {
    const int t = threadIdx.x;
    float sumsq = 0.f;
#pragma unroll
    for (int d = 0; d < 128; d += 4) {
      float4 v = *(const float4*)(ctr + (size_t)t * 128 + d);
      sumsq += v.x * v.x + v.y * v.y + v.z * v.z + v.w * v.w;
      s16x4 o;
      o[0] = f2bf(v.x); o[1] = f2bf(v.y); o[2] = f2bf(v.z); o[3] = f2bf(v.w);
      *(s16x4*)(c16 + (size_t)t * 128 + d) = o;
    }
    csq[t] = sumsq;
    float sc = __expf(ls[t]);
    float iv = 1.0f / (sc + 1e-6f);
    inv2[t] = -0.5f * iv * iv;
    amp[t] = __expf(la[t]);
  }
}

// ---------------------------------------------------------------------------
// bf16 MFMA GEMM, register-pipelined (round-12 exact) — QKV only.
// ---------------------------------------------------------------------------
template <int N, bool SCATTER>
__global__ __launch_bounds__(256) void gemm_bf16(
    const short* __restrict__ A, const short* __restrict__ Wt,
    const float* __restrict__ bias,
    float* __restrict__ out0, float* __restrict__ out1, float* __restrict__ out2) {
  const int tid = threadIdx.x;
  const int w = tid >> 6, l = tid & 63;
  const int lm = l & 15, lk = l >> 4;
  const int n0 = blockIdx.x * 128 + (w & 1) * 64;
  const int m0 = blockIdx.y * 128 + (w >> 1) * 64;
  const int K = 1024;
  f32x4 acc[4][4];
#pragma unroll
  for (int mi = 0; mi < 4; mi++)
#pragma unroll
    for (int ni = 0; ni < 4; ni++) acc[mi][ni] = (f32x4){0.f, 0.f, 0.f, 0.f};

  const short* Ab = A + (size_t)(m0 + lm) * K + lk * 8;
  const short* Bb = Wt + (size_t)(n0 + lm) * K + lk * 8;

  s16x8 af[4], bf[4], an[4], bn[4];
#pragma unroll
  for (int i = 0; i < 4; i++) {
    af[i] = *(const s16x8*)(Ab + (size_t)i * 16 * K);
    bf[i] = *(const s16x8*)(Bb + (size_t)i * 16 * K);
  }
  for (int k0 = 0; k0 < K; k0 += 64) {
#pragma unroll
    for (int i = 0; i < 4; i++) {
      an[i] = *(const s16x8*)(Ab + (size_t)i * 16 * K + k0 + 32);
      bn[i] = *(const s16x8*)(Bb + (size_t)i * 16 * K + k0 + 32);
    }
#pragma unroll
    for (int mi = 0; mi < 4; mi++)
#pragma unroll
      for (int ni = 0; ni < 4; ni++)
        acc[mi][ni] = MFMA_BF16(af[mi], bf[ni], acc[mi][ni]);
    if (k0 + 64 < K) {
#pragma unroll
      for (int i = 0; i < 4; i++) {
        af[i] = *(const s16x8*)(Ab + (size_t)i * 16 * K + k0 + 64);
        bf[i] = *(const s16x8*)(Bb + (size_t)i * 16 * K + k0 + 64);
      }
    }
#pragma unroll
    for (int mi = 0; mi < 4; mi++)
#pragma unroll
      for (int ni = 0; ni < 4; ni++)
        acc[mi][ni] = MFMA_BF16(an[mi], bn[ni], acc[mi][ni]);
  }
#pragma unroll
  for (int ni = 0; ni < 4; ni++) {
    const int n = n0 + ni * 16 + lm;
    const float bv = bias[n];
#pragma unroll
    for (int mi = 0; mi < 4; mi++) {
#pragma unroll
      for (int r = 0; r < 4; r++) {
        const int m = m0 + mi * 16 + lk * 4 + r;
        float v = acc[mi][ni][r] + bv;
        if (SCATTER) {
          int three = n >> 10;
          int h = (n >> 7) & 7;
          int dh = n & 127;
          int bb = m >> 11, tt = m & 2047;
          float* dst = (three == 0) ? out0 : ((three == 1) ? out1 : out2);
          dst[((size_t)(bb * 8 + h) * 2048 + tt) * 128 + dh] = v;
        } else {
          out0[(size_t)m * N + n] = v;
        }
      }
    }
  }
}

// ---------------------------------------------------------------------------
// Merged: splat_mfma (blocks 0..1023) + transpose_v (blocks 1024..5119).
// Round-16 exact.
// ---------------------------------------------------------------------------
__global__ __launch_bounds__(256) void splat_tv(
    const float* __restrict__ qT, const float* __restrict__ kT,
    const short* __restrict__ c16, const float* __restrict__ csq,
    const float* __restrict__ inv2, const float* __restrict__ amp,
    short* __restrict__ qa16, short* __restrict__ kw16,
    const float* __restrict__ vT, short* __restrict__ vt16) {
  __shared__ float tile[32][33];
  const int tid = threadIdx.x;
  if (blockIdx.x < 1024) {
    const int it = blockIdx.x & 31;
    const int bh = (blockIdx.x >> 5) & 15;
    const int which = blockIdx.x >> 9;
    const int w = tid >> 6, l = tid & 63;
    const int lm = l & 15, lk = l >> 4;
    const int h = bh & 7;
    const int i0 = it * 64 + w * 16;
    const float* src = which ? kT : qT;

    s16x8 af[4];
    float sq = 0.f;
#pragma unroll
    for (int kk = 0; kk < 4; kk++) {
      const float* p = src + ((size_t)bh * 2048 + i0 + lm) * 128 + kk * 32 + lk * 8;
      float4 v0 = *(const float4*)p;
      float4 v1 = *(const float4*)(p + 4);
      sq += v0.x * v0.x + v0.y * v0.y + v0.z * v0.z + v0.w * v0.w +
            v1.x * v1.x + v1.y * v1.y + v1.z * v1.z + v1.w * v1.w;
      af[kk][0] = f2bf(v0.x); af[kk][1] = f2bf(v0.y);
      af[kk][2] = f2bf(v0.z); af[kk][3] = f2bf(v0.w);
      af[kk][4] = f2bf(v1.x); af[kk][5] = f2bf(v1.y);
      af[kk][6] = f2bf(v1.z); af[kk][7] = f2bf(v1.w);
    }
    sq += __shfl_xor(sq, 16);
    sq += __shfl_xor(sq, 32);

    f32x4 acc[2];
    acc[0] = (f32x4){0.f, 0.f, 0.f, 0.f};
    acc[1] = (f32x4){0.f, 0.f, 0.f, 0.f};
#pragma unroll
    for (int kk = 0; kk < 4; kk++) {
      s16x8 b0 = *(const s16x8*)(c16 + (size_t)(h * 32 + lm) * 128 + kk * 32 + lk * 8);
      s16x8 b1 = *(const s16x8*)(c16 + (size_t)(h * 32 + 16 + lm) * 128 + kk * 32 + lk * 8);
      acc[0] = MFMA_BF16(af[kk], b0, acc[0]);
      acc[1] = MFMA_BF16(af[kk], b1, acc[1]);
    }
    short* dst = which ? kw16 : qa16;
#pragma unroll
    for (int ni = 0; ni < 2; ni++) {
      const int n = ni * 16 + lm;
      const float cs = csq[h * 32 + n];
      const float iv2 = inv2[h * 32 + n];
      const float am = which ? 1.0f : amp[h * 32 + n];
#pragma unroll
      for (int r = 0; r < 4; r++) {
        float qs = __shfl(sq, lk * 4 + r);
        float d2 = fmaxf(qs + cs - 2.0f * acc[ni][r], 0.0f);
        float wv = __expf(iv2 * d2) * am;
        int m = i0 + lk * 4 + r;
        dst[((size_t)bh * 2048 + m) * 32 + n] = f2bf(wv);
      }
    }
  } else {
    const int idx = blockIdx.x - 1024;
    const int t0 = (idx & 63) * 32;
    const int d0 = ((idx >> 6) & 3) * 32;
    const int bh = idx >> 8;
    const int r = tid >> 3, c4 = (tid & 7) * 4;
    float4 v = *(const float4*)(vT + ((size_t)(bh * 2048 + t0 + r)) * 128 + d0 + c4);
    tile[r][c4 + 0] = v.x; tile[r][c4 + 1] = v.y;
    tile[r][c4 + 2] = v.z; tile[r][c4 + 3] = v.w;
    __syncthreads();
    s16x4 o;
    o[0] = f2bf(tile[c4 + 0][r]);
    o[1] = f2bf(tile[c4 + 1][r]);
    o[2] = f2bf(tile[c4 + 2][r]);
    o[3] = f2bf(tile[c4 + 3][r]);
    *(s16x4*)(vt16 + ((size_t)(bh * 128 + d0 + r)) * 2048 + t0 + c4) = o;
  }
}

// ---------------------------------------------------------------------------
// Flash attention v6 (round-12/11 exact: j-split, NO prefetch).
// ---------------------------------------------------------------------------
__global__ __launch_bounds__(256) void attn_flash(
    const short* __restrict__ qa16, const short* __restrict__ kw16,
    const short* __restrict__ vt16, const float* __restrict__ temp,
    float* __restrict__ lpart, float* __restrict__ accf) {
  __shared__ float pads[4][16][66];
  const int tid = threadIdx.x;
  const int w = tid >> 6, l = tid & 63;
  const int lm = l & 15, lk = l >> 4;
  const int it = blockIdx.x, h = blockIdx.y;
  const int b = blockIdx.z & 1, jh = blockIdx.z >> 1;
  const int bh = b * 8 + h;
  const int i0 = it * 64 + w * 16;
  const float invT = 1.0f / temp[0];
  const short* kwb = kw16 + (size_t)bh * 2048 * 32;
  const short* vtb = vt16 + (size_t)bh * 128 * 2048;
  s16x8 qfrag = *(const s16x8*)(qa16 + ((size_t)(bh * 2048 + i0 + lm)) * 32 + lk * 8);
  float lsum[4] = {0.f, 0.f, 0.f, 0.f};
  f32x4 acc[8];
#pragma unroll
  for (int d = 0; d < 8; d++) acc[d] = (f32x4){0.f, 0.f, 0.f, 0.f};
  float (*pw)[66] = pads[w];

  const int j0 = jh * 1024;
  for (int jc = j0; jc < j0 + 1024; jc += 64) {
    s16x8 kb[4];
#pragma unroll
    for (int c = 0; c < 4; c++)
      kb[c] = *(const s16x8*)(kwb + (size_t)(jc + c * 16 + lm) * 32 + lk * 8);
    f32x4 z = (f32x4){0.f, 0.f, 0.f, 0.f};
    f32x4 s[4];
#pragma unroll
    for (int c = 0; c < 4; c++) s[c] = MFMA_BF16(qfrag, kb[c], z);
    float p[4][4];
#pragma unroll
    for (int r = 0; r < 4; r++) {
      p[0][r] = __expf(s[0][r] * invT);
      p[1][r] = __expf(s[1][r] * invT);
      p[2][r] = __expf(s[2][r] * invT);
      p[3][r] = __expf(s[3][r] * invT);
      lsum[r] += (p[0][r] + p[1][r]) + (p[2][r] + p[3][r]);
    }
#pragma unroll
    for (int c = 0; c < 4; c++)
#pragma unroll
      for (int r = 0; r < 4; r++) pw[lk * 4 + r][c * 16 + lm] = p[c][r];
    s16x8 pf0, pf1;
#pragma unroll
    for (int j = 0; j < 8; j++) {
      pf0[j] = f2bf(pw[lm][lk * 8 + j]);
      pf1[j] = f2bf(pw[lm][32 + lk * 8 + j]);
    }
#pragma unroll
    for (int d = 0; d < 8; d++) {
      const short* vrow = vtb + (size_t)(d * 16 + lm) * 2048 + jc;
      s16x8 vb0 = *(const s16x8*)(vrow + lk * 8);
      s16x8 vb1 = *(const s16x8*)(vrow + 32 + lk * 8);
      acc[d] = MFMA_BF16(pf0, vb0, acc[d]);
      acc[d] = MFMA_BF16(pf1, vb1, acc[d]);
    }
  }
#pragma unroll
  for (int r = 0; r < 4; r++) {
    float rs = lsum[r];
    rs += __shfl_xor(rs, 1);
    rs += __shfl_xor(rs, 2);
    rs += __shfl_xor(rs, 4);
    rs += __shfl_xor(rs, 8);
    lsum[r] = rs;
  }
  float* af = accf + (size_t)jh * 4194304;
#pragma unroll
  for (int r = 0; r < 4; r++) {
    int row = i0 + lk * 4 + r;
    float* ob = af + (size_t)(b * 2048 + row) * 1024 + h * 128 + lm;
#pragma unroll
    for (int d = 0; d < 8; d++) ob[d * 16] = acc[d][r];
  }
  if (lm == 0) {
#pragma unroll
    for (int r = 0; r < 4; r++)
      lpart[jh * 32768 + bh * 2048 + i0 + lk * 4 + r] = lsum[r];
  }
}

// ---------------------------------------------------------------------------
// Merged: gemm_out (blocks 0..255, inline accf normalization — replaces the
// old attn_combine + aout16 path with bit-identical math) + attn_write v5
// (blocks 256..8447, reads lpart directly).  Both depend only on attn_flash.
// ---------------------------------------------------------------------------
__global__ __launch_bounds__(256) void attnw_gemmo(
    const short* __restrict__ qa16, const short* __restrict__ kw16,
    const float* __restrict__ lpart, const float* __restrict__ temp,
    float* __restrict__ attn,
    const float* __restrict__ accf, const short* __restrict__ Wot16,
    const float* __restrict__ bout, float* __restrict__ out) {
  __shared__ float pl[8][32][33];
  const int tid = threadIdx.x;
  const int w = tid >> 6, l = tid & 63;
  const int lm = l & 15, lk = l >> 4;
  if (blockIdx.x < 256) {
    // ---- gemm_out: out = ((accf0+accf1)*invl -> bf16) @ Wot16^T + bout ----
    const int idx = blockIdx.x;
    const int n0 = (idx & 7) * 128 + (w & 1) * 64;
    const int m0 = (idx >> 3) * 128 + (w >> 1) * 64;
    const int K = 1024;
    f32x4 acc[4][4];
#pragma unroll
    for (int mi = 0; mi < 4; mi++)
#pragma unroll
      for (int ni = 0; ni < 4; ni++) acc[mi][ni] = (f32x4){0.f, 0.f, 0.f, 0.f};
    int irow[4], brow[4];
#pragma unroll
    for (int mi = 0; mi < 4; mi++) {
      int m = m0 + mi * 16 + lm;
      irow[mi] = m & 2047;
      brow[mi] = m >> 11;
    }
    const short* Bb = Wot16 + (size_t)(n0 + lm) * K + lk * 8;
    float invl[4];
    for (int k0 = 0; k0 < K; k0 += 32) {
      if ((k0 & 127) == 0) {
        const int h = k0 >> 7;   // uniform: (k0 + lk*8)>>7 == k0>>7
#pragma unroll
        for (int mi = 0; mi < 4; mi++) {
          int bhrow = (brow[mi] * 8 + h) * 2048 + irow[mi];
          invl[mi] = 1.0f / (lpart[bhrow] + lpart[32768 + bhrow]);
        }
      }
      s16x8 af[4], bf[4];
#pragma unroll
      for (int mi = 0; mi < 4; mi++) {
        size_t base = (size_t)(m0 + mi * 16 + lm) * K + k0 + lk * 8;
        float4 x0 = *(const float4*)(accf + base);
        float4 x1 = *(const float4*)(accf + base + 4);
        float4 y0 = *(const float4*)(accf + 4194304 + base);
        float4 y1 = *(const float4*)(accf + 4194304 + base + 4);
        const float iv = invl[mi];
        af[mi][0] = f2bf((x0.x + y0.x) * iv);
        af[mi][1] = f2bf((x0.y + y0.y) * iv);
        af[mi][2] = f2bf((x0.z + y0.z) * iv);
        af[mi][3] = f2bf((x0.w + y0.w) * iv);
        af[mi][4] = f2bf((x1.x + y1.x) * iv);
        af[mi][5] = f2bf((x1.y + y1.y) * iv);
        af[mi][6] = f2bf((x1.z + y1.z) * iv);
        af[mi][7] = f2bf((x1.w + y1.w) * iv);
      }
#pragma unroll
      for (int ni = 0; ni < 4; ni++)
        bf[ni] = *(const s16x8*)(Bb + (size_t)ni * 16 * K + k0);
#pragma unroll
      for (int mi = 0; mi < 4; mi++)
#pragma unroll
        for (int ni = 0; ni < 4; ni++)
          acc[mi][ni] = MFMA_BF16(af[mi], bf[ni], acc[mi][ni]);
    }
#pragma unroll
    for (int ni = 0; ni < 4; ni++) {
      const int n = n0 + ni * 16 + lm;
      const float bv = bout[n];
#pragma unroll
      for (int mi = 0; mi < 4; mi++) {
#pragma unroll
        for (int r = 0; r < 4; r++) {
          const int m = m0 + mi * 16 + lk * 4 + r;
          out[(size_t)m * 1024 + n] = acc[mi][ni][r] + bv;
        }
      }
    }
  } else {
    // ---- attn_write v5 (nt stores; l from lpart) ----
    const int bx = blockIdx.x - 256;
    const int i0 = (bx & 63) * 32, j0 = ((bx >> 6) & 63) * 32, b = bx >> 12;
    const float invT = 1.0f / temp[0];
#pragma unroll
    for (int hh = 0; hh < 2; hh++) {
      const int h = w * 2 + hh;
      const int bh = b * 8 + h;
      s16x8 qf[2], kf[2];
#pragma unroll
      for (int ih = 0; ih < 2; ih++)
        qf[ih] = *(const s16x8*)(qa16 + ((size_t)(bh * 2048 + i0 + ih * 16 + lm)) * 32 + lk * 8);
#pragma unroll
      for (int jh = 0; jh < 2; jh++)
        kf[jh] = *(const s16x8*)(kw16 + ((size_t)(bh * 2048 + j0 + jh * 16 + lm)) * 32 + lk * 8);
      float il[2][4];
#pragma unroll
      for (int ih = 0; ih < 2; ih++)
#pragma unroll
        for (int r = 0; r < 4; r++) {
          int bhrow = bh * 2048 + i0 + ih * 16 + lk * 4 + r;
          il[ih][r] = 1.0f / (lpart[bhrow] + lpart[32768 + bhrow]);
        }
      f32x4 z = (f32x4){0.f, 0.f, 0.f, 0.f};
#pragma unroll
      for (int ih = 0; ih < 2; ih++) {
#pragma unroll
        for (int jh = 0; jh < 2; jh++) {
          f32x4 s = MFMA_BF16(qf[ih], kf[jh], z);
#pragma unroll
          for (int r = 0; r < 4; r++) {
            float p = __expf(s[r] * invT) * il[ih][r];
            pl[h][ih * 16 + lk * 4 + r][jh * 16 + lm] = p;
          }
        }
      }
    }
    __syncthreads();
#pragma unroll
    for (int c = 0; c < 8; c++) {
      int u = c * 256 + tid;
      int i = u >> 6, rem = u & 63;
      int j = rem >> 1, h4 = (rem & 1) * 4;
      f32x4 v;
      v[0] = pl[h4][i][j];
      v[1] = pl[h4 + 1][i][j];
      v[2] = pl[h4 + 2][i][j];
      v[3] = pl[h4 + 3][i][j];
      f32x4* dst = (f32x4*)(attn + (((size_t)(b * 2048 + i0 + i)) * 2048 + j0 + j) * 8 + h4);
      __builtin_nontemporal_store(v, dst);
    }
  }
}

// ---------------------------------------------------------------------------
extern "C" void kernel_launch(void* const* d_in, const int* in_sizes, int n_in,
                              void* d_out, int out_size, void* d_ws, size_t ws_size,
                              hipStream_t stream) {
  const float* x    = (const float*)d_in[0];
  const float* Wqkv = (const float*)d_in[1];
  const float* bqkv = (const float*)d_in[2];
  const float* Wout = (const float*)d_in[3];
  const float* bout = (const float*)d_in[4];
  const float* ctr  = (const float*)d_in[5];
  const float* ls   = (const float*)d_in[6];
  const float* la   = (const float*)d_in[7];
  const float* temp = (const float*)d_in[8];

  float* out = (float*)d_out;                 // (B,T,D)
  float* attn = out + 4194304;                // (B,T,T,H)

  float* ws = (float*)d_ws;
  float* qT    = ws;                          // 4,194,304 fl
  float* kT    = qT + 4194304;
  float* vT    = kT + 4194304;
  short* x16   = (short*)(vT + 4194304);      // 4,194,304 sh
  short* Wqt16 = x16 + 4194304;               // 3,145,728 sh
  short* Wot16 = Wqt16 + 3145728;             // 1,048,576 sh
  short* qa16  = Wot16 + 1048576;             // 1,048,576 sh
  short* kw16  = qa16 + 1048576;
  float* lpart = (float*)(kw16 + 1048576);    // 2 x 32,768 fl
  float* lrow  = lpart + 65536;               // 32,768 fl (unused now)
  float* csq   = lrow + 32768;                // 256
  float* inv2  = csq + 256;
  float* amp   = inv2 + 256;
  short* c16   = (short*)(amp + 256);         // 32,768 sh
  float* accf  = (float*)(c16 + 32768);       // 8,388,608 fl (32 MB)
  short* vt16  = (short*)ws;                  // aliases qT (dead after splat_tv)

  prep_fused<<<8193, 256, 0, stream>>>(x, x16, Wqkv, Wqt16, Wout, Wot16,
                                       ctr, ls, la, c16, csq, inv2, amp);
  gemm_bf16<3072, true><<<dim3(24, 32), 256, 0, stream>>>(
      x16, Wqt16, bqkv, qT, kT, vT);
  splat_tv<<<5120, 256, 0, stream>>>(
      qT, kT, c16, csq, inv2, amp, qa16, kw16, vT, vt16);
  attn_flash<<<dim3(32, 8, 4), 256, 0, stream>>>(
      qa16, kw16, vt16, temp, lpart, accf);
  attnw_gemmo<<<8448, 256, 0, stream>>>(
      qa16, kw16, lpart, temp, attn, accf, Wot16, bout, out);
}

// Round 18
// 600.854 us; speedup vs baseline: 1.0646x; 1.0646x over previous
//
#include <hip/hip_runtime.h>
#include <math.h>

// Shapes: B=2, T=2048, D=1024, H=8, S=32, Dh=128, 3D=3072, B*T=4096
// ROUND-16 EXACT (session best, 605.1 us): pipelined GEMMs, splat_tv merge,
// j-split max-free flash, combine, attnw_gemmo merge with nt stores.
// Round 17's combine-elimination regressed (+35 us) and is reverted.

typedef __attribute__((ext_vector_type(8))) short s16x8;
typedef __attribute__((ext_vector_type(4))) short s16x4;
typedef __attribute__((ext_vector_type(4))) float f32x4;

__device__ inline short f2bf(float f) {
  union { float f; unsigned u; } v; v.f = f;
  unsigned r = v.u + 0x7FFFu + ((v.u >> 16) & 1u);
  return (short)(r >> 16);
}
#define MFMA_BF16(a, b, c) __builtin_amdgcn_mfma_f32_16x16x32_bf16((a), (b), (c), 0, 0, 0)

// ---------------------------------------------------------------------------
// Fused prep (round-8 exact).
// ---------------------------------------------------------------------------
__device__ inline void transpose_tile32(const float* __restrict__ W,
                                        short* __restrict__ Wt, int K, int N,
                                        int n0, int k0) {
  __shared__ float tile[32][33];
  const int r = threadIdx.x >> 3, c4 = (threadIdx.x & 7) * 4;
  float4 v = *(const float4*)(W + (size_t)(k0 + r) * N + n0 + c4);
  tile[r][c4 + 0] = v.x; tile[r][c4 + 1] = v.y;
  tile[r][c4 + 2] = v.z; tile[r][c4 + 3] = v.w;
  __syncthreads();
  s16x4 o;
  o[0] = f2bf(tile[c4 + 0][r]);
  o[1] = f2bf(tile[c4 + 1][r]);
  o[2] = f2bf(tile[c4 + 2][r]);
  o[3] = f2bf(tile[c4 + 3][r]);
  *(s16x4*)(Wt + (size_t)(n0 + r) * K + k0 + c4) = o;
}

__global__ __launch_bounds__(256) void prep_fused(
    const float* __restrict__ x, short* __restrict__ x16,
    const float* __restrict__ Wqkv, short* __restrict__ Wqt16,
    const float* __restrict__ Wout, short* __restrict__ Wot16,
    const float* __restrict__ ctr, const float* __restrict__ ls,
    const float* __restrict__ la, short* __restrict__ c16,
    float* __restrict__ csq, float* __restrict__ inv2, float* __restrict__ amp) {
  const int bx = blockIdx.x;
  if (bx < 4096) {
    int i = bx * 256 + threadIdx.x;
    float4 v = ((const float4*)x)[i];
    s16x4 o;
    o[0] = f2bf(v.x); o[1] = f2bf(v.y); o[2] = f2bf(v.z); o[3] = f2bf(v.w);
    ((s16x4*)x16)[i] = o;
  } else if (bx < 7168) {
    int idx = bx - 4096;
    transpose_tile32(Wqkv, Wqt16, 1024, 3072, (idx % 96) * 32, (idx / 96) * 32);
  } else if (bx < 8192) {
    int idx = bx - 7168;
    transpose_tile32(Wout, Wot16, 1024, 1024, (idx % 32) * 32, (idx / 32) * 32);
  } else {
    const int t = threadIdx.x;
    float sumsq = 0.f;
#pragma unroll
    for (int d = 0; d < 128; d += 4) {
      float4 v = *(const float4*)(ctr + (size_t)t * 128 + d);
      sumsq += v.x * v.x + v.y * v.y + v.z * v.z + v.w * v.w;
      s16x4 o;
      o[0] = f2bf(v.x); o[1] = f2bf(v.y); o[2] = f2bf(v.z); o[3] = f2bf(v.w);
      *(s16x4*)(c16 + (size_t)t * 128 + d) = o;
    }
    csq[t] = sumsq;
    float sc = __expf(ls[t]);
    float iv = 1.0f / (sc + 1e-6f);
    inv2[t] = -0.5f * iv * iv;
    amp[t] = __expf(la[t]);
  }
}

// ---------------------------------------------------------------------------
// bf16 MFMA GEMM, register-pipelined (round-12 exact) — used for QKV only.
// ---------------------------------------------------------------------------
template <int N, bool SCATTER>
__global__ __launch_bounds__(256) void gemm_bf16(
    const short* __restrict__ A, const short* __restrict__ Wt,
    const float* __restrict__ bias,
    float* __restrict__ out0, float* __restrict__ out1, float* __restrict__ out2) {
  const int tid = threadIdx.x;
  const int w = tid >> 6, l = tid & 63;
  const int lm = l & 15, lk = l >> 4;
  const int n0 = blockIdx.x * 128 + (w & 1) * 64;
  const int m0 = blockIdx.y * 128 + (w >> 1) * 64;
  const int K = 1024;
  f32x4 acc[4][4];
#pragma unroll
  for (int mi = 0; mi < 4; mi++)
#pragma unroll
    for (int ni = 0; ni < 4; ni++) acc[mi][ni] = (f32x4){0.f, 0.f, 0.f, 0.f};

  const short* Ab = A + (size_t)(m0 + lm) * K + lk * 8;
  const short* Bb = Wt + (size_t)(n0 + lm) * K + lk * 8;

  s16x8 af[4], bf[4], an[4], bn[4];
#pragma unroll
  for (int i = 0; i < 4; i++) {
    af[i] = *(const s16x8*)(Ab + (size_t)i * 16 * K);
    bf[i] = *(const s16x8*)(Bb + (size_t)i * 16 * K);
  }
  for (int k0 = 0; k0 < K; k0 += 64) {
#pragma unroll
    for (int i = 0; i < 4; i++) {
      an[i] = *(const s16x8*)(Ab + (size_t)i * 16 * K + k0 + 32);
      bn[i] = *(const s16x8*)(Bb + (size_t)i * 16 * K + k0 + 32);
    }
#pragma unroll
    for (int mi = 0; mi < 4; mi++)
#pragma unroll
      for (int ni = 0; ni < 4; ni++)
        acc[mi][ni] = MFMA_BF16(af[mi], bf[ni], acc[mi][ni]);
    if (k0 + 64 < K) {
#pragma unroll
      for (int i = 0; i < 4; i++) {
        af[i] = *(const s16x8*)(Ab + (size_t)i * 16 * K + k0 + 64);
        bf[i] = *(const s16x8*)(Bb + (size_t)i * 16 * K + k0 + 64);
      }
    }
#pragma unroll
    for (int mi = 0; mi < 4; mi++)
#pragma unroll
      for (int ni = 0; ni < 4; ni++)
        acc[mi][ni] = MFMA_BF16(an[mi], bn[ni], acc[mi][ni]);
  }
#pragma unroll
  for (int ni = 0; ni < 4; ni++) {
    const int n = n0 + ni * 16 + lm;
    const float bv = bias[n];
#pragma unroll
    for (int mi = 0; mi < 4; mi++) {
#pragma unroll
      for (int r = 0; r < 4; r++) {
        const int m = m0 + mi * 16 + lk * 4 + r;
        float v = acc[mi][ni][r] + bv;
        if (SCATTER) {
          int three = n >> 10;
          int h = (n >> 7) & 7;
          int dh = n & 127;
          int bb = m >> 11, tt = m & 2047;
          float* dst = (three == 0) ? out0 : ((three == 1) ? out1 : out2);
          dst[((size_t)(bb * 8 + h) * 2048 + tt) * 128 + dh] = v;
        } else {
          out0[(size_t)m * N + n] = v;
        }
      }
    }
  }
}

// ---------------------------------------------------------------------------
// Merged: splat_mfma (blocks 0..1023) + transpose_v (blocks 1024..5119).
// ---------------------------------------------------------------------------
__global__ __launch_bounds__(256) void splat_tv(
    const float* __restrict__ qT, const float* __restrict__ kT,
    const short* __restrict__ c16, const float* __restrict__ csq,
    const float* __restrict__ inv2, const float* __restrict__ amp,
    short* __restrict__ qa16, short* __restrict__ kw16,
    const float* __restrict__ vT, short* __restrict__ vt16) {
  __shared__ float tile[32][33];
  const int tid = threadIdx.x;
  if (blockIdx.x < 1024) {
    const int it = blockIdx.x & 31;
    const int bh = (blockIdx.x >> 5) & 15;
    const int which = blockIdx.x >> 9;
    const int w = tid >> 6, l = tid & 63;
    const int lm = l & 15, lk = l >> 4;
    const int h = bh & 7;
    const int i0 = it * 64 + w * 16;
    const float* src = which ? kT : qT;

    s16x8 af[4];
    float sq = 0.f;
#pragma unroll
    for (int kk = 0; kk < 4; kk++) {
      const float* p = src + ((size_t)bh * 2048 + i0 + lm) * 128 + kk * 32 + lk * 8;
      float4 v0 = *(const float4*)p;
      float4 v1 = *(const float4*)(p + 4);
      sq += v0.x * v0.x + v0.y * v0.y + v0.z * v0.z + v0.w * v0.w +
            v1.x * v1.x + v1.y * v1.y + v1.z * v1.z + v1.w * v1.w;
      af[kk][0] = f2bf(v0.x); af[kk][1] = f2bf(v0.y);
      af[kk][2] = f2bf(v0.z); af[kk][3] = f2bf(v0.w);
      af[kk][4] = f2bf(v1.x); af[kk][5] = f2bf(v1.y);
      af[kk][6] = f2bf(v1.z); af[kk][7] = f2bf(v1.w);
    }
    sq += __shfl_xor(sq, 16);
    sq += __shfl_xor(sq, 32);

    f32x4 acc[2];
    acc[0] = (f32x4){0.f, 0.f, 0.f, 0.f};
    acc[1] = (f32x4){0.f, 0.f, 0.f, 0.f};
#pragma unroll
    for (int kk = 0; kk < 4; kk++) {
      s16x8 b0 = *(const s16x8*)(c16 + (size_t)(h * 32 + lm) * 128 + kk * 32 + lk * 8);
      s16x8 b1 = *(const s16x8*)(c16 + (size_t)(h * 32 + 16 + lm) * 128 + kk * 32 + lk * 8);
      acc[0] = MFMA_BF16(af[kk], b0, acc[0]);
      acc[1] = MFMA_BF16(af[kk], b1, acc[1]);
    }
    short* dst = which ? kw16 : qa16;
#pragma unroll
    for (int ni = 0; ni < 2; ni++) {
      const int n = ni * 16 + lm;
      const float cs = csq[h * 32 + n];
      const float iv2 = inv2[h * 32 + n];
      const float am = which ? 1.0f : amp[h * 32 + n];
#pragma unroll
      for (int r = 0; r < 4; r++) {
        float qs = __shfl(sq, lk * 4 + r);
        float d2 = fmaxf(qs + cs - 2.0f * acc[ni][r], 0.0f);
        float wv = __expf(iv2 * d2) * am;
        int m = i0 + lk * 4 + r;
        dst[((size_t)bh * 2048 + m) * 32 + n] = f2bf(wv);
      }
    }
  } else {
    const int idx = blockIdx.x - 1024;
    const int t0 = (idx & 63) * 32;
    const int d0 = ((idx >> 6) & 3) * 32;
    const int bh = idx >> 8;
    const int r = tid >> 3, c4 = (tid & 7) * 4;
    float4 v = *(const float4*)(vT + ((size_t)(bh * 2048 + t0 + r)) * 128 + d0 + c4);
    tile[r][c4 + 0] = v.x; tile[r][c4 + 1] = v.y;
    tile[r][c4 + 2] = v.z; tile[r][c4 + 3] = v.w;
    __syncthreads();
    s16x4 o;
    o[0] = f2bf(tile[c4 + 0][r]);
    o[1] = f2bf(tile[c4 + 1][r]);
    o[2] = f2bf(tile[c4 + 2][r]);
    o[3] = f2bf(tile[c4 + 3][r]);
    *(s16x4*)(vt16 + ((size_t)(bh * 128 + d0 + r)) * 2048 + t0 + c4) = o;
  }
}

// ---------------------------------------------------------------------------
// Flash attention v6 (j-split, max-free, no prefetch).
// ---------------------------------------------------------------------------
__global__ __launch_bounds__(256) void attn_flash(
    const short* __restrict__ qa16, const short* __restrict__ kw16,
    const short* __restrict__ vt16, const float* __restrict__ temp,
    float* __restrict__ lpart, float* __restrict__ accf) {
  __shared__ float pads[4][16][66];
  const int tid = threadIdx.x;
  const int w = tid >> 6, l = tid & 63;
  const int lm = l & 15, lk = l >> 4;
  const int it = blockIdx.x, h = blockIdx.y;
  const int b = blockIdx.z & 1, jh = blockIdx.z >> 1;
  const int bh = b * 8 + h;
  const int i0 = it * 64 + w * 16;
  const float invT = 1.0f / temp[0];
  const short* kwb = kw16 + (size_t)bh * 2048 * 32;
  const short* vtb = vt16 + (size_t)bh * 128 * 2048;
  s16x8 qfrag = *(const s16x8*)(qa16 + ((size_t)(bh * 2048 + i0 + lm)) * 32 + lk * 8);
  float lsum[4] = {0.f, 0.f, 0.f, 0.f};
  f32x4 acc[8];
#pragma unroll
  for (int d = 0; d < 8; d++) acc[d] = (f32x4){0.f, 0.f, 0.f, 0.f};
  float (*pw)[66] = pads[w];

  const int j0 = jh * 1024;
  for (int jc = j0; jc < j0 + 1024; jc += 64) {
    s16x8 kb[4];
#pragma unroll
    for (int c = 0; c < 4; c++)
      kb[c] = *(const s16x8*)(kwb + (size_t)(jc + c * 16 + lm) * 32 + lk * 8);
    f32x4 z = (f32x4){0.f, 0.f, 0.f, 0.f};
    f32x4 s[4];
#pragma unroll
    for (int c = 0; c < 4; c++) s[c] = MFMA_BF16(qfrag, kb[c], z);
    float p[4][4];
#pragma unroll
    for (int r = 0; r < 4; r++) {
      p[0][r] = __expf(s[0][r] * invT);
      p[1][r] = __expf(s[1][r] * invT);
      p[2][r] = __expf(s[2][r] * invT);
      p[3][r] = __expf(s[3][r] * invT);
      lsum[r] += (p[0][r] + p[1][r]) + (p[2][r] + p[3][r]);
    }
#pragma unroll
    for (int c = 0; c < 4; c++)
#pragma unroll
      for (int r = 0; r < 4; r++) pw[lk * 4 + r][c * 16 + lm] = p[c][r];
    s16x8 pf0, pf1;
#pragma unroll
    for (int j = 0; j < 8; j++) {
      pf0[j] = f2bf(pw[lm][lk * 8 + j]);
      pf1[j] = f2bf(pw[lm][32 + lk * 8 + j]);
    }
#pragma unroll
    for (int d = 0; d < 8; d++) {
      const short* vrow = vtb + (size_t)(d * 16 + lm) * 2048 + jc;
      s16x8 vb0 = *(const s16x8*)(vrow + lk * 8);
      s16x8 vb1 = *(const s16x8*)(vrow + 32 + lk * 8);
      acc[d] = MFMA_BF16(pf0, vb0, acc[d]);
      acc[d] = MFMA_BF16(pf1, vb1, acc[d]);
    }
  }
#pragma unroll
  for (int r = 0; r < 4; r++) {
    float rs = lsum[r];
    rs += __shfl_xor(rs, 1);
    rs += __shfl_xor(rs, 2);
    rs += __shfl_xor(rs, 4);
    rs += __shfl_xor(rs, 8);
    lsum[r] = rs;
  }
  float* af = accf + (size_t)jh * 4194304;
#pragma unroll
  for (int r = 0; r < 4; r++) {
    int row = i0 + lk * 4 + r;
    float* ob = af + (size_t)(b * 2048 + row) * 1024 + h * 128 + lm;
#pragma unroll
    for (int d = 0; d < 8; d++) ob[d * 16] = acc[d][r];
  }
  if (lm == 0) {
#pragma unroll
    for (int r = 0; r < 4; r++)
      lpart[jh * 32768 + bh * 2048 + i0 + lk * 4 + r] = lsum[r];
  }
}

// ---------------------------------------------------------------------------
// Combine (round-11 exact).
// ---------------------------------------------------------------------------
__global__ __launch_bounds__(256) void attn_combine(
    const float* __restrict__ accf, const float* __restrict__ lpart,
    short* __restrict__ aout16, float* __restrict__ lrow) {
  const int m = blockIdx.x;
  const int b = m >> 11, i = m & 2047;
  const int t = threadIdx.x;
  const int n = t * 4;
  const int h = n >> 7;
  const int bhrow = (b * 8 + h) * 2048 + i;
  const float l0 = lpart[bhrow], l1 = lpart[32768 + bhrow];
  const float lv = l0 + l1;
  const float invl = 1.0f / lv;
  float4 v0 = *(const float4*)(accf + (size_t)m * 1024 + n);
  float4 v1 = *(const float4*)(accf + 4194304 + (size_t)m * 1024 + n);
  s16x4 o;
  o[0] = f2bf((v0.x + v1.x) * invl);
  o[1] = f2bf((v0.y + v1.y) * invl);
  o[2] = f2bf((v0.z + v1.z) * invl);
  o[3] = f2bf((v0.w + v1.w) * invl);
  *(s16x4*)(aout16 + (size_t)m * 1024 + n) = o;
  if ((n & 127) == 0) lrow[bhrow] = lv;
}

// ---------------------------------------------------------------------------
// Merged: gemm_out (blocks 0..255, first) + attn_write v5 (256..8447, nt).
// ---------------------------------------------------------------------------
__global__ __launch_bounds__(256) void attnw_gemmo(
    const short* __restrict__ qa16, const short* __restrict__ kw16,
    const float* __restrict__ lrow, const float* __restrict__ temp,
    float* __restrict__ attn,
    const short* __restrict__ aout16, const short* __restrict__ Wot16,
    const float* __restrict__ bout, float* __restrict__ out) {
  __shared__ float pl[8][32][33];
  const int tid = threadIdx.x;
  const int w = tid >> 6, l = tid & 63;
  const int lm = l & 15, lk = l >> 4;
  if (blockIdx.x < 256) {
    const int idx = blockIdx.x;
    const int n0 = (idx & 7) * 128 + (w & 1) * 64;
    const int m0 = (idx >> 3) * 128 + (w >> 1) * 64;
    const int K = 1024;
    f32x4 acc[4][4];
#pragma unroll
    for (int mi = 0; mi < 4; mi++)
#pragma unroll
      for (int ni = 0; ni < 4; ni++) acc[mi][ni] = (f32x4){0.f, 0.f, 0.f, 0.f};
    const short* Ab = aout16 + (size_t)(m0 + lm) * K + lk * 8;
    const short* Bb = Wot16 + (size_t)(n0 + lm) * K + lk * 8;
    s16x8 af[4], bf[4], an[4], bn[4];
#pragma unroll
    for (int i = 0; i < 4; i++) {
      af[i] = *(const s16x8*)(Ab + (size_t)i * 16 * K);
      bf[i] = *(const s16x8*)(Bb + (size_t)i * 16 * K);
    }
    for (int k0 = 0; k0 < K; k0 += 64) {
#pragma unroll
      for (int i = 0; i < 4; i++) {
        an[i] = *(const s16x8*)(Ab + (size_t)i * 16 * K + k0 + 32);
        bn[i] = *(const s16x8*)(Bb + (size_t)i * 16 * K + k0 + 32);
      }
#pragma unroll
      for (int mi = 0; mi < 4; mi++)
#pragma unroll
        for (int ni = 0; ni < 4; ni++)
          acc[mi][ni] = MFMA_BF16(af[mi], bf[ni], acc[mi][ni]);
      if (k0 + 64 < K) {
#pragma unroll
        for (int i = 0; i < 4; i++) {
          af[i] = *(const s16x8*)(Ab + (size_t)i * 16 * K + k0 + 64);
          bf[i] = *(const s16x8*)(Bb + (size_t)i * 16 * K + k0 + 64);
        }
      }
#pragma unroll
      for (int mi = 0; mi < 4; mi++)
#pragma unroll
        for (int ni = 0; ni < 4; ni++)
          acc[mi][ni] = MFMA_BF16(an[mi], bn[ni], acc[mi][ni]);
    }
#pragma unroll
    for (int ni = 0; ni < 4; ni++) {
      const int n = n0 + ni * 16 + lm;
      const float bv = bout[n];
#pragma unroll
      for (int mi = 0; mi < 4; mi++) {
#pragma unroll
        for (int r = 0; r < 4; r++) {
          const int m = m0 + mi * 16 + lk * 4 + r;
          out[(size_t)m * 1024 + n] = acc[mi][ni][r] + bv;
        }
      }
    }
  } else {
    const int bx = blockIdx.x - 256;
    const int i0 = (bx & 63) * 32, j0 = ((bx >> 6) & 63) * 32, b = bx >> 12;
    const float invT = 1.0f / temp[0];
#pragma unroll
    for (int hh = 0; hh < 2; hh++) {
      const int h = w * 2 + hh;
      const int bh = b * 8 + h;
      s16x8 qf[2], kf[2];
#pragma unroll
      for (int ih = 0; ih < 2; ih++)
        qf[ih] = *(const s16x8*)(qa16 + ((size_t)(bh * 2048 + i0 + ih * 16 + lm)) * 32 + lk * 8);
#pragma unroll
      for (int jh = 0; jh < 2; jh++)
        kf[jh] = *(const s16x8*)(kw16 + ((size_t)(bh * 2048 + j0 + jh * 16 + lm)) * 32 + lk * 8);
      float il[2][4];
#pragma unroll
      for (int ih = 0; ih < 2; ih++)
#pragma unroll
        for (int r = 0; r < 4; r++)
          il[ih][r] = 1.0f / lrow[bh * 2048 + i0 + ih * 16 + lk * 4 + r];
      f32x4 z = (f32x4){0.f, 0.f, 0.f, 0.f};
#pragma unroll
      for (int ih = 0; ih < 2; ih++) {
#pragma unroll
        for (int jh = 0; jh < 2; jh++) {
          f32x4 s = MFMA_BF16(qf[ih], kf[jh], z);
#pragma unroll
          for (int r = 0; r < 4; r++) {
            float p = __expf(s[r] * invT) * il[ih][r];
            pl[h][ih * 16 + lk * 4 + r][jh * 16 + lm] = p;
          }
        }
      }
    }
    __syncthreads();
#pragma unroll
    for (int c = 0; c < 8; c++) {
      int u = c * 256 + tid;
      int i = u >> 6, rem = u & 63;
      int j = rem >> 1, h4 = (rem & 1) * 4;
      f32x4 v;
      v[0] = pl[h4][i][j];
      v[1] = pl[h4 + 1][i][j];
      v[2] = pl[h4 + 2][i][j];
      v[3] = pl[h4 + 3][i][j];
      f32x4* dst = (f32x4*)(attn + (((size_t)(b * 2048 + i0 + i)) * 2048 + j0 + j) * 8 + h4);
      __builtin_nontemporal_store(v, dst);
    }
  }
}

// ---------------------------------------------------------------------------
extern "C" void kernel_launch(void* const* d_in, const int* in_sizes, int n_in,
                              void* d_out, int out_size, void* d_ws, size_t ws_size,
                              hipStream_t stream) {
  const float* x    = (const float*)d_in[0];
  const float* Wqkv = (const float*)d_in[1];
  const float* bqkv = (const float*)d_in[2];
  const float* Wout = (const float*)d_in[3];
  const float* bout = (const float*)d_in[4];
  const float* ctr  = (const float*)d_in[5];
  const float* ls   = (const float*)d_in[6];
  const float* la   = (const float*)d_in[7];
  const float* temp = (const float*)d_in[8];

  float* out = (float*)d_out;                 // (B,T,D)
  float* attn = out + 4194304;                // (B,T,T,H)

  float* ws = (float*)d_ws;
  float* qT    = ws;                          // 4,194,304 fl
  float* kT    = qT + 4194304;
  float* vT    = kT + 4194304;
  short* x16   = (short*)(vT + 4194304);      // 4,194,304 sh
  short* Wqt16 = x16 + 4194304;               // 3,145,728 sh
  short* Wot16 = Wqt16 + 3145728;             // 1,048,576 sh
  short* qa16  = Wot16 + 1048576;             // 1,048,576 sh
  short* kw16  = qa16 + 1048576;
  float* lpart = (float*)(kw16 + 1048576);    // 2 x 32,768 fl
  float* lrow  = lpart + 65536;               // 32,768 fl
  float* csq   = lrow + 32768;                // 256
  float* inv2  = csq + 256;
  float* amp   = inv2 + 256;
  short* c16   = (short*)(amp + 256);         // 32,768 sh
  float* accf  = (float*)(c16 + 32768);       // 8,388,608 fl (32 MB)
  short* vt16  = (short*)ws;                  // aliases qT   (dead after splat_tv)
  short* aout16 = (short*)vT;                 // aliases vT   (dead after splat_tv)

  prep_fused<<<8193, 256, 0, stream>>>(x, x16, Wqkv, Wqt16, Wout, Wot16,
                                       ctr, ls, la, c16, csq, inv2, amp);
  gemm_bf16<3072, true><<<dim3(24, 32), 256, 0, stream>>>(
      x16, Wqt16, bqkv, qT, kT, vT);
  splat_tv<<<5120, 256, 0, stream>>>(
      qT, kT, c16, csq, inv2, amp, qa16, kw16, vT, vt16);
  attn_flash<<<dim3(32, 8, 4), 256, 0, stream>>>(
      qa16, kw16, vt16, temp, lpart, accf);
  attn_combine<<<4096, 256, 0, stream>>>(accf, lpart, aout16, lrow);
  attnw_gemmo<<<8448, 256, 0, stream>>>(
      qa16, kw16, lrow, temp, attn, aout16, Wot16, bout, out);
}